// Round 3
// baseline (424.614 us; speedup 1.0000x reference)
//
#include <hip/hip_runtime.h>
#include <hip/hip_bf16.h>
#include <cstdint>
#include <cstddef>

typedef _Float16 half8 __attribute__((ext_vector_type(8)));
typedef _Float16 half4 __attribute__((ext_vector_type(4)));
typedef float f32x4 __attribute__((ext_vector_type(4)));

#define NB 4
#define NL 1024
#define NHD 512
#define NH 8
#define ND 64
#define NBH 32

#define MFMA16(a, b, c) __builtin_amdgcn_mfma_f32_16x16x32_f16((a), (b), (c), 0, 0, 0)

// ---------------------------------------------------------------------------
// PREP pass (streaming, all-coalesced). Two block ranges:
//  blocks [0,4096):  mask bit-pack (R0's proven kernel, verbatim): 32M elems
//    -> 1M words, bit i of word t = elem 32t+i. Per-block dtype
//    self-detection (byte masks trip a non-{0,1,0x3F800000} word w.p. ~1).
//  blocks [4096,6144): kern re-block: kblk[bh][qt][k][64] = kern[bh][k][qt*64+64)
//    Read: 16B/lane fully coalesced (1KB/wave-instr). Write: 4x256B chunks
//    per wave-instr; consecutive k from consecutive threads -> L2
//    write-combines into contiguous per-qt streams.
//  WHY: attn consumed kern in 256B-per-row stripes (64-col q-tiles of a
//  row-major [k][q] matrix) -> temporally scattered 128B DRAM requests ->
//  1.5TB/s (24% peak) and a 115us attn. Blocked layout makes each attn
//  (block,tile) bias read a dense 16KB chunk; a block's 8 tiles are a
//  contiguous 128KB stream.
// ---------------------------------------------------------------------------
__global__ __launch_bounds__(256) void prep_kernel(
    const float* __restrict__ kern, const void* __restrict__ mask,
    float* __restrict__ kblk, unsigned* __restrict__ mb)
{
    const int tid = threadIdx.x;
    if (blockIdx.x < 4096) {
        // ---- mask bit-pack ----
        __shared__ int s_byte;
        const int t = blockIdx.x * 256 + tid;
        if (tid == 0) s_byte = 0;
        __syncthreads();

        const uint4* p = (const uint4*)((const unsigned char*)mask + (size_t)t * 32);
        uint4 a = p[0], b = p[1];
        unsigned src[8] = {a.x, a.y, a.z, a.w, b.x, b.y, b.z, b.w};
        int bad = 0;
#pragma unroll
        for (int j = 0; j < 8; ++j)
            if (src[j] != 0u && src[j] != 1u && src[j] != 0x3F800000u) bad = 1;
        if (bad) atomicOr(&s_byte, 1);
        __syncthreads();

        unsigned w = 0;
        if (s_byte) {
            // byte elements: the 32 bytes already in src are this thread's 32 elems
#pragma unroll
            for (int j = 0; j < 8; ++j) {
                unsigned u = src[j];
                w |= ((u & 0x000000FFu) ? 1u : 0u) << (4 * j + 0);
                w |= ((u & 0x0000FF00u) ? 1u : 0u) << (4 * j + 1);
                w |= ((u & 0x00FF0000u) ? 1u : 0u) << (4 * j + 2);
                w |= ((u & 0xFF000000u) ? 1u : 0u) << (4 * j + 3);
            }
        } else {
            // 4-byte elements (int32 {0,1} or f32 {0,1.0f}): re-read 32 words
            const uint4* q = (const uint4*)((const unsigned*)mask + (size_t)t * 32);
#pragma unroll
            for (int j = 0; j < 8; ++j) {
                uint4 v = q[j];
                w |= (v.x ? 1u : 0u) << (4 * j + 0);
                w |= (v.y ? 1u : 0u) << (4 * j + 1);
                w |= (v.z ? 1u : 0u) << (4 * j + 2);
                w |= (v.w ? 1u : 0u) << (4 * j + 3);
            }
        }
        mb[t] = w;
    } else {
        // ---- kern re-block: 8M 16B-chunks, 16 per thread, coalesced ----
        const int bid2 = blockIdx.x - 4096;
        unsigned ch = bid2 * 256 + tid;           // [0, 524288) base
#pragma unroll
        for (int i = 0; i < 16; ++i, ch += 524288) {
            const unsigned c16 = ch & 255;        // 16B chunk within row
            const unsigned k   = (ch >> 8) & 1023;
            const unsigned bh  = ch >> 18;
            const unsigned qt  = c16 >> 4;
            const unsigned qq  = (c16 & 15) * 4;
            f32x4 v = *(const f32x4*)(kern + (size_t)ch * 4);
            *(f32x4*)(kblk + (((size_t)(bh * 16 + qt) * 1024) + k) * 64 + qq) = v;
        }
    }
}

// ---------------------------------------------------------------------------
// QKV projection: out = X @ W_p^T + b_p  (M=4096, N=512, K=512), f16 MFMA.
// BM=128, BN=64, BK=64. proj 0 -> qb (pre-scaled 0.125), 1 -> kb,
// 2 -> vtb (transposed [bh][d][l]).
// ---------------------------------------------------------------------------
__global__ __launch_bounds__(256) void qkv_gemm_kernel(
    const float* __restrict__ qin, const float* __restrict__ kin, const float* __restrict__ vin,
    const float* __restrict__ w, const float* __restrict__ bias,
    _Float16* __restrict__ qb, _Float16* __restrict__ kb, _Float16* __restrict__ vtb)
{
    const int mtile = blockIdx.x, ntile = blockIdx.y, proj = blockIdx.z;
    const float* A = proj == 0 ? qin : (proj == 1 ? kin : vin);
    const float* W = w + (size_t)proj * NHD * NHD;

    __shared__ __align__(16) _Float16 a_lds[128][72];
    __shared__ __align__(16) _Float16 b_lds[64][72];

    const int tid = threadIdx.x;
    const int wave = tid >> 6, lane = tid & 63, quad = lane >> 4, c = lane & 15;
    const int wm = wave >> 1, wn = wave & 1;

    f32x4 acc[4][2] = {};

    const int arow = tid >> 1, acol = (tid & 1) * 32;
    const int brow = tid >> 2, bcol = (tid & 3) * 16;
    const float* pa = &A[(size_t)(mtile * 128 + arow) * NHD + acol];
    const float* pb = &W[(size_t)(ntile * 64 + brow) * NHD + bcol];

    f32x4 ar[8], br[4];
#pragma unroll
    for (int j = 0; j < 8; ++j) ar[j] = *(const f32x4*)(pa + j * 4);
#pragma unroll
    for (int j = 0; j < 4; ++j) br[j] = *(const f32x4*)(pb + j * 4);

    for (int k0 = 0; k0 < NHD; k0 += 64) {
        half8 ah[4], bh_[2];
#pragma unroll
        for (int t = 0; t < 4; ++t)
#pragma unroll
            for (int j = 0; j < 4; ++j) {
                ah[t][j] = (_Float16)ar[2 * t][j];
                ah[t][4 + j] = (_Float16)ar[2 * t + 1][j];
            }
#pragma unroll
        for (int t = 0; t < 2; ++t)
#pragma unroll
            for (int j = 0; j < 4; ++j) {
                bh_[t][j] = (_Float16)br[2 * t][j];
                bh_[t][4 + j] = (_Float16)br[2 * t + 1][j];
            }
        __syncthreads();
#pragma unroll
        for (int t = 0; t < 4; ++t) *(half8*)&a_lds[arow][acol + t * 8] = ah[t];
#pragma unroll
        for (int t = 0; t < 2; ++t) *(half8*)&b_lds[brow][bcol + t * 8] = bh_[t];
        if (k0 < NHD - 64) {
            const float* na = pa + k0 + 64;
            const float* nb = pb + k0 + 64;
#pragma unroll
            for (int j = 0; j < 8; ++j) ar[j] = *(const f32x4*)(na + j * 4);
#pragma unroll
            for (int j = 0; j < 4; ++j) br[j] = *(const f32x4*)(nb + j * 4);
        }
        __syncthreads();

#pragma unroll
        for (int kk = 0; kk < 2; ++kk) {
            half8 af[4], bf[2];
#pragma unroll
            for (int ms = 0; ms < 4; ++ms)
                af[ms] = *(const half8*)&a_lds[wm * 64 + ms * 16 + c][kk * 32 + quad * 8];
#pragma unroll
            for (int ns = 0; ns < 2; ++ns)
                bf[ns] = *(const half8*)&b_lds[wn * 32 + ns * 16 + c][kk * 32 + quad * 8];
#pragma unroll
            for (int ms = 0; ms < 4; ++ms)
#pragma unroll
                for (int ns = 0; ns < 2; ++ns)
                    acc[ms][ns] = MFMA16(af[ms], bf[ns], acc[ms][ns]);
        }
    }

#pragma unroll
    for (int ms = 0; ms < 4; ++ms)
#pragma unroll
    for (int ns = 0; ns < 2; ++ns) {
        const int Cc = ntile * 64 + wn * 32 + ns * 16 + c;
        const float bv = bias[proj * NHD + Cc];
        const int h = Cc >> 6, d = Cc & 63;
#pragma unroll
        for (int r = 0; r < 4; ++r) {
            const int R = mtile * 128 + wm * 64 + ms * 16 + quad * 4 + r;
            const int b = R >> 10, l = R & 1023;
            const int bh = b * NH + h;
            float val = acc[ms][ns][r] + bv;
            if (proj == 0) {
                qb[((size_t)(bh * NL + l)) * ND + d] = (_Float16)(val * 0.125f);
            } else if (proj == 1) {
                kb[((size_t)(bh * NL + l)) * ND + d] = (_Float16)val;
            } else {
                vtb[((size_t)(bh * ND + d)) * NL + l] = (_Float16)val;
            }
        }
    }
}

// ---------------------------------------------------------------------------
// Flash attention, SPLIT-K x2: block (qt, bh, half) processes 8 of 16 k-tiles.
// R2: bias from kblk (blocked layout, dense 16KB/tile, contiguous across
// tiles) in registers; mask from 4MB bit-packed mb. Post-barrier prefetch
// of K/V/mask kept from R1.
// ---------------------------------------------------------------------------
__global__ __launch_bounds__(256) void attn_kernel(
    const _Float16* __restrict__ qb, const _Float16* __restrict__ kb, const _Float16* __restrict__ vtb,
    const float* __restrict__ kblk, const unsigned* __restrict__ mb,
    _Float16* __restrict__ pO, float* __restrict__ pm, float* __restrict__ pl)
{
    const int qt = blockIdx.x, bh = blockIdx.y, half = blockIdx.z;
    const int tid = threadIdx.x, wave = tid >> 6, lane = tid & 63, quad = lane >> 4, c = lane & 15;
    const int q_base = qt * 64 + wave * 16;
    const int kt0 = half * 8;

    __shared__ __align__(16) _Float16 k_lds[64][72];
    __shared__ __align__(16) _Float16 vt_lds[64][72];
    __shared__ __align__(16) _Float16 p_lds[64][72];
    __shared__ unsigned mask_lds[64][2];               // [q][k-word]

    half8 aq0 = *(const half8*)&qb[((size_t)(bh * NL) + q_base + c) * ND + quad * 8];
    half8 aq1 = *(const half8*)&qb[((size_t)(bh * NL) + q_base + c) * ND + 32 + quad * 8];

    f32x4 O[4] = {};
    float m_i[4] = {-1e30f, -1e30f, -1e30f, -1e30f};
    float l_i[4] = {0.f, 0.f, 0.f, 0.f};

    const int sr = tid >> 2, sc = (tid & 3) * 16;

    half8 kr0, kr1, vr0, vr1;
    unsigned mr = 0;
    f32x4 bias_r[4];

    // blocked bias: kblk[bh][qt][k][q']; per-lane offset within a k-tile.
    // element (k = ns*16+c, q' = wave*16+quad*4+r) = tile_base + (ns*16+c)*64
    //   + wave*16 + quad*4 + r   -> f32x4 over r. Dense 16KB per (block,tile).
    const float* bias_tile0 = kblk + ((size_t)(bh * 16 + qt) * 1024 + kt0 * 64) * 64;
    const int bias_lane_off = c * 64 + wave * 16 + quad * 4;

    // prologue: K/V/mask then bias for tile kt0 (bias issued last: in-order
    // retirement keeps its wait decoupled from the K/V LDS-store wait).
    {
        const _Float16* pk = &kb[((size_t)(bh * NL) + kt0 * 64 + sr) * ND + sc];
        kr0 = *(const half8*)pk; kr1 = *(const half8*)(pk + 8);
        const _Float16* pv = &vtb[((size_t)(bh * ND) + sr) * NL + kt0 * 64 + sc];
        vr0 = *(const half8*)pv; vr1 = *(const half8*)(pv + 8);
        if (tid < 128) mr = mb[((size_t)bh * NL + qt * 64 + (tid >> 1)) * 32 + kt0 * 2 + (tid & 1)];
#pragma unroll
        for (int ns = 0; ns < 4; ++ns)
            bias_r[ns] = *(const f32x4*)(bias_tile0 + ns * 16 * 64 + bias_lane_off);
    }

    for (int kt = 0; kt < 8; ++kt) {
        __syncthreads();
        *(half8*)&k_lds[sr][sc] = kr0;  *(half8*)&k_lds[sr][sc + 8] = kr1;
        *(half8*)&vt_lds[sr][sc] = vr0; *(half8*)&vt_lds[sr][sc + 8] = vr1;
        if (tid < 128) mask_lds[tid >> 1][tid & 1] = mr;
        __syncthreads();

        // prefetch K/V/mask for tile kt+1 (after barrier: stays in flight
        // across the whole compute phase)
        if (kt < 7) {
            const int ktg = kt0 + kt + 1;
            const _Float16* pk = &kb[((size_t)(bh * NL) + ktg * 64 + sr) * ND + sc];
            kr0 = *(const half8*)pk; kr1 = *(const half8*)(pk + 8);
            const _Float16* pv = &vtb[((size_t)(bh * ND) + sr) * NL + ktg * 64 + sc];
            vr0 = *(const half8*)pv; vr1 = *(const half8*)(pv + 8);
            if (tid < 128) mr = mb[((size_t)bh * NL + qt * 64 + (tid >> 1)) * 32 + ktg * 2 + (tid & 1)];
        }

        // S = (q*scale) @ k^T
        f32x4 S[4];
#pragma unroll
        for (int ns = 0; ns < 4; ++ns) {
            f32x4 a = {};
            half8 bk0 = *(const half8*)&k_lds[ns * 16 + c][quad * 8];
            half8 bk1 = *(const half8*)&k_lds[ns * 16 + c][32 + quad * 8];
            a = MFMA16(aq0, bk0, a);
            a = MFMA16(aq1, bk1, a);
            S[ns] = a;
        }

        unsigned mw0[4], mw1[4];
#pragma unroll
        for (int r = 0; r < 4; ++r) {
            const int row = wave * 16 + quad * 4 + r;
            uint2 mm = *(const uint2*)&mask_lds[row][0];
            mw0[r] = mm.x; mw1[r] = mm.y;
        }

        // + kernel^T from registers (bias_r prefetched one tile ahead)
#pragma unroll
        for (int ns = 0; ns < 4; ++ns) {
            const int bit = ((ns & 1) << 4) + c;
#pragma unroll
            for (int r = 0; r < 4; ++r) {
                unsigned w = (ns < 2) ? mw0[r] : mw1[r];
                bool mk = (w >> bit) & 1u;
                S[ns][r] = mk ? -1e30f : (S[ns][r] + bias_r[ns][r]);
            }
        }

        // bias_r now free -> issue bias prefetch for tile kt+1
        if (kt < 7) {
            const float* bt = bias_tile0 + (size_t)(kt + 1) * 64 * 64;
#pragma unroll
            for (int ns = 0; ns < 4; ++ns)
                bias_r[ns] = *(const f32x4*)(bt + ns * 16 * 64 + bias_lane_off);
        }

        // online softmax across this tile's 64 k-cols
        float pmax[4], al[4];
#pragma unroll
        for (int r = 0; r < 4; ++r) {
            float t = fmaxf(fmaxf(S[0][r], S[1][r]), fmaxf(S[2][r], S[3][r]));
            t = fmaxf(t, __shfl_xor(t, 1));
            t = fmaxf(t, __shfl_xor(t, 2));
            t = fmaxf(t, __shfl_xor(t, 4));
            t = fmaxf(t, __shfl_xor(t, 8));
            float mn = fmaxf(m_i[r], t);
            al[r] = __expf(m_i[r] - mn);
            m_i[r] = mn;
            pmax[r] = mn;
        }
        float rs[4] = {0.f, 0.f, 0.f, 0.f};
#pragma unroll
        for (int ns = 0; ns < 4; ++ns)
#pragma unroll
            for (int r = 0; r < 4; ++r) {
                float p = __expf(S[ns][r] - pmax[r]);
                S[ns][r] = p;
                rs[r] += p;
            }
#pragma unroll
        for (int r = 0; r < 4; ++r) {
            float t = rs[r];
            t += __shfl_xor(t, 1);
            t += __shfl_xor(t, 2);
            t += __shfl_xor(t, 4);
            t += __shfl_xor(t, 8);
            l_i[r] = l_i[r] * al[r] + t;
        }
#pragma unroll
        for (int ds = 0; ds < 4; ++ds)
#pragma unroll
            for (int r = 0; r < 4; ++r)
                O[ds][r] *= al[r];

        // P (C-layout) -> LDS -> A-layout; wave-local rows, lgkmcnt suffices.
#pragma unroll
        for (int ns = 0; ns < 4; ++ns)
#pragma unroll
            for (int r = 0; r < 4; ++r)
                p_lds[wave * 16 + quad * 4 + r][ns * 16 + c] = (_Float16)S[ns][r];
        __asm__ volatile("s_waitcnt lgkmcnt(0)" ::: "memory");

#pragma unroll
        for (int ks = 0; ks < 2; ++ks) {
            half8 ap = *(const half8*)&p_lds[wave * 16 + c][ks * 32 + quad * 8];
#pragma unroll
            for (int ds = 0; ds < 4; ++ds) {
                half8 bv = *(const half8*)&vt_lds[ds * 16 + c][ks * 32 + quad * 8];
                O[ds] = MFMA16(ap, bv, O[ds]);
            }
        }
    }

    // write unnormalized partial (f16) + per-row (m, l)
    const int ub = (bh * 16 + qt) * 2 + half;
    _Float16* pOb = pO + (size_t)ub * 4096;
#pragma unroll
    for (int ds = 0; ds < 4; ++ds)
#pragma unroll
        for (int r = 0; r < 4; ++r)
            pOb[(wave * 16 + quad * 4 + r) * 64 + ds * 16 + c] = (_Float16)O[ds][r];
    if (c == 0) {
#pragma unroll
        for (int r = 0; r < 4; ++r) {
            const int row = wave * 16 + quad * 4 + r;
            pm[(size_t)ub * 64 + row] = m_i[r];
            pl[(size_t)ub * 64 + row] = l_i[r];
        }
    }
}

// ---------------------------------------------------------------------------
// Output projection FUSED with split-K merge: A-tile staging merges the two
// f16 partials (scales from pm/pl) during the LDS store. 64-row mtile = one
// (b, qt); each 64-col k0 block = one head h -> u0 = ((b*8+h)*16+qt)*2.
// ---------------------------------------------------------------------------
__global__ __launch_bounds__(256) void out_gemm_kernel(
    const _Float16* __restrict__ pO, const float* __restrict__ pm, const float* __restrict__ pl,
    const float* __restrict__ w, const float* __restrict__ bias,
    float* __restrict__ out)
{
    const int mtile = blockIdx.x, ntile = blockIdx.y;
    const int bb = mtile >> 4, qt = mtile & 15;
    __shared__ __align__(16) _Float16 a_lds[64][72];
    __shared__ __align__(16) _Float16 b_lds[64][72];
    const int tid = threadIdx.x, wave = tid >> 6, lane = tid & 63, quad = lane >> 4, c = lane & 15;
    const int wm = wave >> 1, wn = wave & 1;
    f32x4 acc[2][2] = {};

    const int sr = tid >> 2, sc = (tid & 3) * 16;

    half8 p0a, p0b, p1a, p1b;
    f32x4 br[4];
    float m0, l0, m1, l1;

    auto fetch = [&](int k0) {
        const int h = k0 >> 6;
        const int u0 = ((bb * 8 + h) * 16 + qt) * 2;
        const _Float16* q0 = pO + (size_t)u0 * 4096 + sr * 64 + sc;
        p0a = *(const half8*)q0; p0b = *(const half8*)(q0 + 8);
        const _Float16* q1 = q0 + 4096;
        p1a = *(const half8*)q1; p1b = *(const half8*)(q1 + 8);
        m0 = pm[(size_t)u0 * 64 + sr]; l0 = pl[(size_t)u0 * 64 + sr];
        m1 = pm[(size_t)(u0 + 1) * 64 + sr]; l1 = pl[(size_t)(u0 + 1) * 64 + sr];
        const float* pb = &w[(size_t)(ntile * 64 + sr) * NHD + k0 + sc];
#pragma unroll
        for (int j = 0; j < 4; ++j) br[j] = *(const f32x4*)(pb + j * 4);
    };

    fetch(0);
    for (int k0 = 0; k0 < NHD; k0 += 64) {
        // merge scales (exact split-K softmax combine)
        const float mx = fmaxf(m0, m1);
        const float e0 = __expf(m0 - mx), e1 = __expf(m1 - mx);
        const float linv = 1.0f / (l0 * e0 + l1 * e1);
        const float s0 = e0 * linv, s1 = e1 * linv;
        half8 ah0, ah1, bh0, bh1;
#pragma unroll
        for (int j = 0; j < 8; ++j) {
            ah0[j] = (_Float16)((float)p0a[j] * s0 + (float)p1a[j] * s1);
            ah1[j] = (_Float16)((float)p0b[j] * s0 + (float)p1b[j] * s1);
        }
#pragma unroll
        for (int j = 0; j < 4; ++j) {
            bh0[j] = (_Float16)br[0][j]; bh0[4 + j] = (_Float16)br[1][j];
            bh1[j] = (_Float16)br[2][j]; bh1[4 + j] = (_Float16)br[3][j];
        }
        __syncthreads();
        *(half8*)&a_lds[sr][sc] = ah0; *(half8*)&a_lds[sr][sc + 8] = ah1;
        *(half8*)&b_lds[sr][sc] = bh0; *(half8*)&b_lds[sr][sc + 8] = bh1;
        if (k0 < NHD - 64) fetch(k0 + 64);
        __syncthreads();

#pragma unroll
        for (int kk = 0; kk < 2; ++kk) {
            half8 af0 = *(const half8*)&a_lds[wm * 32 + c][kk * 32 + quad * 8];
            half8 af1 = *(const half8*)&a_lds[wm * 32 + 16 + c][kk * 32 + quad * 8];
            half8 bf0 = *(const half8*)&b_lds[wn * 32 + c][kk * 32 + quad * 8];
            half8 bf1 = *(const half8*)&b_lds[wn * 32 + 16 + c][kk * 32 + quad * 8];
            acc[0][0] = MFMA16(af0, bf0, acc[0][0]);
            acc[0][1] = MFMA16(af0, bf1, acc[0][1]);
            acc[1][0] = MFMA16(af1, bf0, acc[1][0]);
            acc[1][1] = MFMA16(af1, bf1, acc[1][1]);
        }
    }

#pragma unroll
    for (int ms = 0; ms < 2; ++ms)
#pragma unroll
    for (int ns = 0; ns < 2; ++ns) {
        const int Cc = ntile * 64 + wn * 32 + ns * 16 + c;
        const float bv = bias[Cc];
#pragma unroll
        for (int r = 0; r < 4; ++r) {
            const int R = mtile * 64 + wm * 32 + ms * 16 + quad * 4 + r;
            out[(size_t)R * NHD + Cc] = acc[ms][ns][r] + bv;
        }
    }
}

extern "C" void kernel_launch(void* const* d_in, const int* in_sizes, int n_in,
                              void* d_out, int out_size, void* d_ws, size_t ws_size,
                              hipStream_t stream)
{
    const float* query = (const float*)d_in[0];
    const float* key_  = (const float*)d_in[1];
    const float* value = (const float*)d_in[2];
    const void*  mask  = d_in[3];
    const float* kern  = (const float*)d_in[5];
    const float* ipw   = (const float*)d_in[6];
    const float* ipb   = (const float*)d_in[7];
    const float* outw  = (const float*)d_in[8];
    const float* outb  = (const float*)d_in[9];

    char* ws = (char*)d_ws;
    _Float16* qb  = (_Float16*)(ws);                    // 4 MB   [BH][L][D]
    _Float16* kb  = (_Float16*)(ws + (4ull << 20));     // 4 MB   [BH][L][D]
    _Float16* vtb = (_Float16*)(ws + (8ull << 20));     // 4 MB   [BH][D][L]
    _Float16* pO  = (_Float16*)(ws + (16ull << 20));    // 8 MB   [1024][64][64] f16
    float* pm     = (float*)(ws + (32ull << 20));       // 256 KB
    float* pl     = (float*)(ws + (33ull << 20));       // 256 KB
    unsigned* mb  = (unsigned*)(ws + (40ull << 20));    // 4 MB
    float* kblk   = (float*)(ws + (48ull << 20));       // 128 MB [BH][16 qt][L k][64 q']

    prep_kernel<<<6144, 256, 0, stream>>>(kern, mask, kblk, mb);
    qkv_gemm_kernel<<<dim3(32, 8, 3), 256, 0, stream>>>(query, key_, value, ipw, ipb, qb, kb, vtb);
    attn_kernel<<<dim3(16, 32, 2), 256, 0, stream>>>(qb, kb, vtb, kblk, mb, pO, pm, pl);
    out_gemm_kernel<<<dim3(64, 8), 256, 0, stream>>>(pO, pm, pl, outw, outb, (float*)d_out);
}

// Round 4
// 398.583 us; speedup vs baseline: 1.0653x; 1.0653x over previous
//
#include <hip/hip_runtime.h>
#include <hip/hip_bf16.h>
#include <cstdint>
#include <cstddef>

typedef _Float16 half8 __attribute__((ext_vector_type(8)));
typedef _Float16 half4 __attribute__((ext_vector_type(4)));
typedef float f32x4 __attribute__((ext_vector_type(4)));

#define NB 4
#define NL 1024
#define NHD 512
#define NH 8
#define ND 64
#define NBH 32

#define MFMA16(a, b, c) __builtin_amdgcn_mfma_f32_16x16x32_f16((a), (b), (c), 0, 0, 0)

// ---------------------------------------------------------------------------
// PREP v2. R3 post-mortem: v1 ran at 2.4 TB/s because the kern path was a
// serialized dependent load->store chain (VGPR=32 proved the 16x unroll
// collapsed) with 256B-granule scattered writes and only 2048 heavy blocks.
// v2: LDS-tiled transpose, dense BOTH sides, f16 output (halves write + the
// later attn read).
//  blocks [0,4096):  kern -> bm f16 blocked. Tile = 32 k-rows x 256 q-cols.
//    decode: bh = bid>>7, kt32 = (bid&127)>>2, qtg = bid&3.
//    Read: 8 instrs x 4KB contiguous (4 rows/instr); consecutive qtg blocks
//    cover each 4KB kern row back-to-back -> dense DRAM streams.
//    Write: per qt-sub (4): 32x64 f16 = 4KB contiguous per instr.
//  blocks [4096,8192): mask bit-pack (proven R0 logic verbatim): 1 word per
//    thread, bit i of word t = elem 32t+i; per-block dtype self-detection.
// bm layout: [bh][qt][k 1024][q' 64] f16, bm = mask-free bias only.
// ---------------------------------------------------------------------------
__global__ __launch_bounds__(256) void prep_kernel(
    const float* __restrict__ kern, const void* __restrict__ mask,
    _Float16* __restrict__ bm, unsigned* __restrict__ mb)
{
    const int tid = threadIdx.x;
    if (blockIdx.x < 4096) {
        // ---- kern re-block to f16, LDS transpose tile 32k x 256q ----
        __shared__ __align__(16) float t_lds[32][268];
        const int bid = blockIdx.x;
        const int bh = bid >> 7, kt32 = (bid & 127) >> 2, qtg = bid & 3;
        const int kbase = kt32 * 32, qbase = qtg * 256;

        // read: 8 x (4 rows x 1KB) fully coalesced
        {
            const int r0 = tid >> 6, col = (tid & 63) * 4;
            const float* src = kern + ((size_t)(bh * NL) + kbase + r0) * NL + qbase + col;
            f32x4 v[8];
#pragma unroll
            for (int i = 0; i < 8; ++i)
                v[i] = *(const f32x4*)(src + (size_t)i * 4 * NL);
#pragma unroll
            for (int i = 0; i < 8; ++i)
                *(f32x4*)&t_lds[i * 4 + r0][col] = v[i];
        }
        __syncthreads();

        // write: 4 qt-subtiles, each 32x64 f16 = 4KB contiguous per instr
        const int row = tid >> 3, qq = (tid & 7) * 8;
#pragma unroll
        for (int qtl = 0; qtl < 4; ++qtl) {
            f32x4 a = *(const f32x4*)&t_lds[row][qtl * 64 + qq];
            f32x4 b = *(const f32x4*)&t_lds[row][qtl * 64 + qq + 4];
            half8 h;
#pragma unroll
            for (int j = 0; j < 4; ++j) { h[j] = (_Float16)a[j]; h[4 + j] = (_Float16)b[j]; }
            const int qt = qtg * 4 + qtl;
            *(half8*)(bm + (((size_t)(bh * 16 + qt) * NL) + kbase + row) * 64 + qq) = h;
        }
    } else {
        // ---- mask bit-pack (R0-proven) ----
        __shared__ int s_byte;
        const int t = (blockIdx.x - 4096) * 256 + tid;
        if (tid == 0) s_byte = 0;
        __syncthreads();

        const uint4* p = (const uint4*)((const unsigned char*)mask + (size_t)t * 32);
        uint4 a = p[0], b = p[1];
        unsigned src[8] = {a.x, a.y, a.z, a.w, b.x, b.y, b.z, b.w};
        int bad = 0;
#pragma unroll
        for (int j = 0; j < 8; ++j)
            if (src[j] != 0u && src[j] != 1u && src[j] != 0x3F800000u) bad = 1;
        if (bad) atomicOr(&s_byte, 1);
        __syncthreads();

        unsigned w = 0;
        if (s_byte) {
            // byte elements: the 32 bytes already in src are this thread's 32 elems
#pragma unroll
            for (int j = 0; j < 8; ++j) {
                unsigned u = src[j];
                w |= ((u & 0x000000FFu) ? 1u : 0u) << (4 * j + 0);
                w |= ((u & 0x0000FF00u) ? 1u : 0u) << (4 * j + 1);
                w |= ((u & 0x00FF0000u) ? 1u : 0u) << (4 * j + 2);
                w |= ((u & 0xFF000000u) ? 1u : 0u) << (4 * j + 3);
            }
        } else {
            // 4-byte elements (int32 {0,1} or f32 {0,1.0f}): re-read 32 words
            const uint4* q = (const uint4*)((const unsigned*)mask + (size_t)t * 32);
#pragma unroll
            for (int j = 0; j < 8; ++j) {
                uint4 v = q[j];
                w |= (v.x ? 1u : 0u) << (4 * j + 0);
                w |= (v.y ? 1u : 0u) << (4 * j + 1);
                w |= (v.z ? 1u : 0u) << (4 * j + 2);
                w |= (v.w ? 1u : 0u) << (4 * j + 3);
            }
        }
        mb[t] = w;
    }
}

// ---------------------------------------------------------------------------
// QKV projection: out = X @ W_p^T + b_p  (M=4096, N=512, K=512), f16 MFMA.
// BM=128, BN=64, BK=64. proj 0 -> qb (pre-scaled 0.125), 1 -> kb,
// 2 -> vtb (transposed [bh][d][l]).
// ---------------------------------------------------------------------------
__global__ __launch_bounds__(256) void qkv_gemm_kernel(
    const float* __restrict__ qin, const float* __restrict__ kin, const float* __restrict__ vin,
    const float* __restrict__ w, const float* __restrict__ bias,
    _Float16* __restrict__ qb, _Float16* __restrict__ kb, _Float16* __restrict__ vtb)
{
    const int mtile = blockIdx.x, ntile = blockIdx.y, proj = blockIdx.z;
    const float* A = proj == 0 ? qin : (proj == 1 ? kin : vin);
    const float* W = w + (size_t)proj * NHD * NHD;

    __shared__ __align__(16) _Float16 a_lds[128][72];
    __shared__ __align__(16) _Float16 b_lds[64][72];

    const int tid = threadIdx.x;
    const int wave = tid >> 6, lane = tid & 63, quad = lane >> 4, c = lane & 15;
    const int wm = wave >> 1, wn = wave & 1;

    f32x4 acc[4][2] = {};

    const int arow = tid >> 1, acol = (tid & 1) * 32;
    const int brow = tid >> 2, bcol = (tid & 3) * 16;
    const float* pa = &A[(size_t)(mtile * 128 + arow) * NHD + acol];
    const float* pb = &W[(size_t)(ntile * 64 + brow) * NHD + bcol];

    f32x4 ar[8], br[4];
#pragma unroll
    for (int j = 0; j < 8; ++j) ar[j] = *(const f32x4*)(pa + j * 4);
#pragma unroll
    for (int j = 0; j < 4; ++j) br[j] = *(const f32x4*)(pb + j * 4);

    for (int k0 = 0; k0 < NHD; k0 += 64) {
        half8 ah[4], bh_[2];
#pragma unroll
        for (int t = 0; t < 4; ++t)
#pragma unroll
            for (int j = 0; j < 4; ++j) {
                ah[t][j] = (_Float16)ar[2 * t][j];
                ah[t][4 + j] = (_Float16)ar[2 * t + 1][j];
            }
#pragma unroll
        for (int t = 0; t < 2; ++t)
#pragma unroll
            for (int j = 0; j < 4; ++j) {
                bh_[t][j] = (_Float16)br[2 * t][j];
                bh_[t][4 + j] = (_Float16)br[2 * t + 1][j];
            }
        __syncthreads();
#pragma unroll
        for (int t = 0; t < 4; ++t) *(half8*)&a_lds[arow][acol + t * 8] = ah[t];
#pragma unroll
        for (int t = 0; t < 2; ++t) *(half8*)&b_lds[brow][bcol + t * 8] = bh_[t];
        if (k0 < NHD - 64) {
            const float* na = pa + k0 + 64;
            const float* nb = pb + k0 + 64;
#pragma unroll
            for (int j = 0; j < 8; ++j) ar[j] = *(const f32x4*)(na + j * 4);
#pragma unroll
            for (int j = 0; j < 4; ++j) br[j] = *(const f32x4*)(nb + j * 4);
        }
        __syncthreads();

#pragma unroll
        for (int kk = 0; kk < 2; ++kk) {
            half8 af[4], bf[2];
#pragma unroll
            for (int ms = 0; ms < 4; ++ms)
                af[ms] = *(const half8*)&a_lds[wm * 64 + ms * 16 + c][kk * 32 + quad * 8];
#pragma unroll
            for (int ns = 0; ns < 2; ++ns)
                bf[ns] = *(const half8*)&b_lds[wn * 32 + ns * 16 + c][kk * 32 + quad * 8];
#pragma unroll
            for (int ms = 0; ms < 4; ++ms)
#pragma unroll
                for (int ns = 0; ns < 2; ++ns)
                    acc[ms][ns] = MFMA16(af[ms], bf[ns], acc[ms][ns]);
        }
    }

#pragma unroll
    for (int ms = 0; ms < 4; ++ms)
#pragma unroll
    for (int ns = 0; ns < 2; ++ns) {
        const int Cc = ntile * 64 + wn * 32 + ns * 16 + c;
        const float bv = bias[proj * NHD + Cc];
        const int h = Cc >> 6, d = Cc & 63;
#pragma unroll
        for (int r = 0; r < 4; ++r) {
            const int R = mtile * 128 + wm * 64 + ms * 16 + quad * 4 + r;
            const int b = R >> 10, l = R & 1023;
            const int bh = b * NH + h;
            float val = acc[ms][ns][r] + bv;
            if (proj == 0) {
                qb[((size_t)(bh * NL + l)) * ND + d] = (_Float16)(val * 0.125f);
            } else if (proj == 1) {
                kb[((size_t)(bh * NL + l)) * ND + d] = (_Float16)val;
            } else {
                vtb[((size_t)(bh * ND + d)) * NL + l] = (_Float16)val;
            }
        }
    }
}

// ---------------------------------------------------------------------------
// Flash attention, SPLIT-K x2: block (qt, bh, half) processes 8 of 16 k-tiles.
// Bias from bm (f16 blocked: dense 8KB/tile, contiguous 64KB stream per
// block); mask from 4MB bit-packed mb. Post-barrier K/V/mask prefetch.
// ---------------------------------------------------------------------------
__global__ __launch_bounds__(256) void attn_kernel(
    const _Float16* __restrict__ qb, const _Float16* __restrict__ kb, const _Float16* __restrict__ vtb,
    const _Float16* __restrict__ bm, const unsigned* __restrict__ mb,
    _Float16* __restrict__ pO, float* __restrict__ pm, float* __restrict__ pl)
{
    const int qt = blockIdx.x, bh = blockIdx.y, half = blockIdx.z;
    const int tid = threadIdx.x, wave = tid >> 6, lane = tid & 63, quad = lane >> 4, c = lane & 15;
    const int q_base = qt * 64 + wave * 16;
    const int kt0 = half * 8;

    __shared__ __align__(16) _Float16 k_lds[64][72];
    __shared__ __align__(16) _Float16 vt_lds[64][72];
    __shared__ __align__(16) _Float16 p_lds[64][72];
    __shared__ unsigned mask_lds[64][2];               // [q][k-word]

    half8 aq0 = *(const half8*)&qb[((size_t)(bh * NL) + q_base + c) * ND + quad * 8];
    half8 aq1 = *(const half8*)&qb[((size_t)(bh * NL) + q_base + c) * ND + 32 + quad * 8];

    f32x4 O[4] = {};
    float m_i[4] = {-1e30f, -1e30f, -1e30f, -1e30f};
    float l_i[4] = {0.f, 0.f, 0.f, 0.f};

    const int sr = tid >> 2, sc = (tid & 3) * 16;

    half8 kr0, kr1, vr0, vr1;
    unsigned mr = 0;
    half4 bias_h[4];

    // blocked f16 bias: bm[bh][qt][k][q']; element (k = ns*16+c,
    // q' = wave*16+quad*4+r) -> half4 over r. Dense 8KB per (block,tile).
    const _Float16* bias_tile0 = bm + ((size_t)(bh * 16 + qt) * NL + kt0 * 64) * 64;
    const int bias_lane_off = c * 64 + wave * 16 + quad * 4;

    // prologue: K/V/mask then bias for tile kt0 (bias issued last: in-order
    // retirement keeps its wait decoupled from the K/V LDS-store wait).
    {
        const _Float16* pk = &kb[((size_t)(bh * NL) + kt0 * 64 + sr) * ND + sc];
        kr0 = *(const half8*)pk; kr1 = *(const half8*)(pk + 8);
        const _Float16* pv = &vtb[((size_t)(bh * ND) + sr) * NL + kt0 * 64 + sc];
        vr0 = *(const half8*)pv; vr1 = *(const half8*)(pv + 8);
        if (tid < 128) mr = mb[((size_t)bh * NL + qt * 64 + (tid >> 1)) * 32 + kt0 * 2 + (tid & 1)];
#pragma unroll
        for (int ns = 0; ns < 4; ++ns)
            bias_h[ns] = *(const half4*)(bias_tile0 + ns * 16 * 64 + bias_lane_off);
    }

    for (int kt = 0; kt < 8; ++kt) {
        __syncthreads();
        *(half8*)&k_lds[sr][sc] = kr0;  *(half8*)&k_lds[sr][sc + 8] = kr1;
        *(half8*)&vt_lds[sr][sc] = vr0; *(half8*)&vt_lds[sr][sc + 8] = vr1;
        if (tid < 128) mask_lds[tid >> 1][tid & 1] = mr;
        __syncthreads();

        // prefetch K/V/mask for tile kt+1 (after barrier: stays in flight
        // across the whole compute phase)
        if (kt < 7) {
            const int ktg = kt0 + kt + 1;
            const _Float16* pk = &kb[((size_t)(bh * NL) + ktg * 64 + sr) * ND + sc];
            kr0 = *(const half8*)pk; kr1 = *(const half8*)(pk + 8);
            const _Float16* pv = &vtb[((size_t)(bh * ND) + sr) * NL + ktg * 64 + sc];
            vr0 = *(const half8*)pv; vr1 = *(const half8*)(pv + 8);
            if (tid < 128) mr = mb[((size_t)bh * NL + qt * 64 + (tid >> 1)) * 32 + ktg * 2 + (tid & 1)];
        }

        // S = (q*scale) @ k^T
        f32x4 S[4];
#pragma unroll
        for (int ns = 0; ns < 4; ++ns) {
            f32x4 a = {};
            half8 bk0 = *(const half8*)&k_lds[ns * 16 + c][quad * 8];
            half8 bk1 = *(const half8*)&k_lds[ns * 16 + c][32 + quad * 8];
            a = MFMA16(aq0, bk0, a);
            a = MFMA16(aq1, bk1, a);
            S[ns] = a;
        }

        unsigned mw0[4], mw1[4];
#pragma unroll
        for (int r = 0; r < 4; ++r) {
            const int row = wave * 16 + quad * 4 + r;
            uint2 mm = *(const uint2*)&mask_lds[row][0];
            mw0[r] = mm.x; mw1[r] = mm.y;
        }

        // + kernel^T from registers (f16 bias prefetched one tile ahead)
#pragma unroll
        for (int ns = 0; ns < 4; ++ns) {
            const int bit = ((ns & 1) << 4) + c;
#pragma unroll
            for (int r = 0; r < 4; ++r) {
                unsigned w = (ns < 2) ? mw0[r] : mw1[r];
                bool mk = (w >> bit) & 1u;
                S[ns][r] = mk ? -1e30f : (S[ns][r] + (float)bias_h[ns][r]);
            }
        }

        // bias_h now free -> issue bias prefetch for tile kt+1
        if (kt < 7) {
            const _Float16* bt = bias_tile0 + (size_t)(kt + 1) * 64 * 64;
#pragma unroll
            for (int ns = 0; ns < 4; ++ns)
                bias_h[ns] = *(const half4*)(bt + ns * 16 * 64 + bias_lane_off);
        }

        // online softmax across this tile's 64 k-cols
        float pmax[4], al[4];
#pragma unroll
        for (int r = 0; r < 4; ++r) {
            float t = fmaxf(fmaxf(S[0][r], S[1][r]), fmaxf(S[2][r], S[3][r]));
            t = fmaxf(t, __shfl_xor(t, 1));
            t = fmaxf(t, __shfl_xor(t, 2));
            t = fmaxf(t, __shfl_xor(t, 4));
            t = fmaxf(t, __shfl_xor(t, 8));
            float mn = fmaxf(m_i[r], t);
            al[r] = __expf(m_i[r] - mn);
            m_i[r] = mn;
            pmax[r] = mn;
        }
        float rs[4] = {0.f, 0.f, 0.f, 0.f};
#pragma unroll
        for (int ns = 0; ns < 4; ++ns)
#pragma unroll
            for (int r = 0; r < 4; ++r) {
                float p = __expf(S[ns][r] - pmax[r]);
                S[ns][r] = p;
                rs[r] += p;
            }
#pragma unroll
        for (int r = 0; r < 4; ++r) {
            float t = rs[r];
            t += __shfl_xor(t, 1);
            t += __shfl_xor(t, 2);
            t += __shfl_xor(t, 4);
            t += __shfl_xor(t, 8);
            l_i[r] = l_i[r] * al[r] + t;
        }
#pragma unroll
        for (int ds = 0; ds < 4; ++ds)
#pragma unroll
            for (int r = 0; r < 4; ++r)
                O[ds][r] *= al[r];

        // P (C-layout) -> LDS -> A-layout; wave-local rows, lgkmcnt suffices.
#pragma unroll
        for (int ns = 0; ns < 4; ++ns)
#pragma unroll
            for (int r = 0; r < 4; ++r)
                p_lds[wave * 16 + quad * 4 + r][ns * 16 + c] = (_Float16)S[ns][r];
        __asm__ volatile("s_waitcnt lgkmcnt(0)" ::: "memory");

#pragma unroll
        for (int ks = 0; ks < 2; ++ks) {
            half8 ap = *(const half8*)&p_lds[wave * 16 + c][ks * 32 + quad * 8];
#pragma unroll
            for (int ds = 0; ds < 4; ++ds) {
                half8 bv = *(const half8*)&vt_lds[ds * 16 + c][ks * 32 + quad * 8];
                O[ds] = MFMA16(ap, bv, O[ds]);
            }
        }
    }

    // write unnormalized partial (f16) + per-row (m, l)
    const int ub = (bh * 16 + qt) * 2 + half;
    _Float16* pOb = pO + (size_t)ub * 4096;
#pragma unroll
    for (int ds = 0; ds < 4; ++ds)
#pragma unroll
        for (int r = 0; r < 4; ++r)
            pOb[(wave * 16 + quad * 4 + r) * 64 + ds * 16 + c] = (_Float16)O[ds][r];
    if (c == 0) {
#pragma unroll
        for (int r = 0; r < 4; ++r) {
            const int row = wave * 16 + quad * 4 + r;
            pm[(size_t)ub * 64 + row] = m_i[r];
            pl[(size_t)ub * 64 + row] = l_i[r];
        }
    }
}

// ---------------------------------------------------------------------------
// Output projection FUSED with split-K merge: A-tile staging merges the two
// f16 partials (scales from pm/pl) during the LDS store. 64-row mtile = one
// (b, qt); each 64-col k0 block = one head h -> u0 = ((b*8+h)*16+qt)*2.
// ---------------------------------------------------------------------------
__global__ __launch_bounds__(256) void out_gemm_kernel(
    const _Float16* __restrict__ pO, const float* __restrict__ pm, const float* __restrict__ pl,
    const float* __restrict__ w, const float* __restrict__ bias,
    float* __restrict__ out)
{
    const int mtile = blockIdx.x, ntile = blockIdx.y;
    const int bb = mtile >> 4, qt = mtile & 15;
    __shared__ __align__(16) _Float16 a_lds[64][72];
    __shared__ __align__(16) _Float16 b_lds[64][72];
    const int tid = threadIdx.x, wave = tid >> 6, lane = tid & 63, quad = lane >> 4, c = lane & 15;
    const int wm = wave >> 1, wn = wave & 1;
    f32x4 acc[2][2] = {};

    const int sr = tid >> 2, sc = (tid & 3) * 16;

    half8 p0a, p0b, p1a, p1b;
    f32x4 br[4];
    float m0, l0, m1, l1;

    auto fetch = [&](int k0) {
        const int h = k0 >> 6;
        const int u0 = ((bb * 8 + h) * 16 + qt) * 2;
        const _Float16* q0 = pO + (size_t)u0 * 4096 + sr * 64 + sc;
        p0a = *(const half8*)q0; p0b = *(const half8*)(q0 + 8);
        const _Float16* q1 = q0 + 4096;
        p1a = *(const half8*)q1; p1b = *(const half8*)(q1 + 8);
        m0 = pm[(size_t)u0 * 64 + sr]; l0 = pl[(size_t)u0 * 64 + sr];
        m1 = pm[(size_t)(u0 + 1) * 64 + sr]; l1 = pl[(size_t)(u0 + 1) * 64 + sr];
        const float* pb = &w[(size_t)(ntile * 64 + sr) * NHD + k0 + sc];
#pragma unroll
        for (int j = 0; j < 4; ++j) br[j] = *(const f32x4*)(pb + j * 4);
    };

    fetch(0);
    for (int k0 = 0; k0 < NHD; k0 += 64) {
        // merge scales (exact split-K softmax combine)
        const float mx = fmaxf(m0, m1);
        const float e0 = __expf(m0 - mx), e1 = __expf(m1 - mx);
        const float linv = 1.0f / (l0 * e0 + l1 * e1);
        const float s0 = e0 * linv, s1 = e1 * linv;
        half8 ah0, ah1, bh0, bh1;
#pragma unroll
        for (int j = 0; j < 8; ++j) {
            ah0[j] = (_Float16)((float)p0a[j] * s0 + (float)p1a[j] * s1);
            ah1[j] = (_Float16)((float)p0b[j] * s0 + (float)p1b[j] * s1);
        }
#pragma unroll
        for (int j = 0; j < 4; ++j) {
            bh0[j] = (_Float16)br[0][j]; bh0[4 + j] = (_Float16)br[1][j];
            bh1[j] = (_Float16)br[2][j]; bh1[4 + j] = (_Float16)br[3][j];
        }
        __syncthreads();
        *(half8*)&a_lds[sr][sc] = ah0; *(half8*)&a_lds[sr][sc + 8] = ah1;
        *(half8*)&b_lds[sr][sc] = bh0; *(half8*)&b_lds[sr][sc + 8] = bh1;
        if (k0 < NHD - 64) fetch(k0 + 64);
        __syncthreads();

#pragma unroll
        for (int kk = 0; kk < 2; ++kk) {
            half8 af0 = *(const half8*)&a_lds[wm * 32 + c][kk * 32 + quad * 8];
            half8 af1 = *(const half8*)&a_lds[wm * 32 + 16 + c][kk * 32 + quad * 8];
            half8 bf0 = *(const half8*)&b_lds[wn * 32 + c][kk * 32 + quad * 8];
            half8 bf1 = *(const half8*)&b_lds[wn * 32 + 16 + c][kk * 32 + quad * 8];
            acc[0][0] = MFMA16(af0, bf0, acc[0][0]);
            acc[0][1] = MFMA16(af0, bf1, acc[0][1]);
            acc[1][0] = MFMA16(af1, bf0, acc[1][0]);
            acc[1][1] = MFMA16(af1, bf1, acc[1][1]);
        }
    }

#pragma unroll
    for (int ms = 0; ms < 2; ++ms)
#pragma unroll
    for (int ns = 0; ns < 2; ++ns) {
        const int Cc = ntile * 64 + wn * 32 + ns * 16 + c;
        const float bv = bias[Cc];
#pragma unroll
        for (int r = 0; r < 4; ++r) {
            const int R = mtile * 64 + wm * 32 + ms * 16 + quad * 4 + r;
            out[(size_t)R * NHD + Cc] = acc[ms][ns][r] + bv;
        }
    }
}

extern "C" void kernel_launch(void* const* d_in, const int* in_sizes, int n_in,
                              void* d_out, int out_size, void* d_ws, size_t ws_size,
                              hipStream_t stream)
{
    const float* query = (const float*)d_in[0];
    const float* key_  = (const float*)d_in[1];
    const float* value = (const float*)d_in[2];
    const void*  mask  = d_in[3];
    const float* kern  = (const float*)d_in[5];
    const float* ipw   = (const float*)d_in[6];
    const float* ipb   = (const float*)d_in[7];
    const float* outw  = (const float*)d_in[8];
    const float* outb  = (const float*)d_in[9];

    char* ws = (char*)d_ws;
    _Float16* qb  = (_Float16*)(ws);                    // 4 MB   [BH][L][D]
    _Float16* kb  = (_Float16*)(ws + (4ull << 20));     // 4 MB   [BH][L][D]
    _Float16* vtb = (_Float16*)(ws + (8ull << 20));     // 4 MB   [BH][D][L]
    _Float16* pO  = (_Float16*)(ws + (16ull << 20));    // 8 MB   [1024][64][64] f16
    float* pm     = (float*)(ws + (32ull << 20));       // 256 KB
    float* pl     = (float*)(ws + (33ull << 20));       // 256 KB
    unsigned* mb  = (unsigned*)(ws + (40ull << 20));    // 4 MB
    _Float16* bm  = (_Float16*)(ws + (48ull << 20));    // 64 MB  [BH][16 qt][L k][64 q'] f16

    prep_kernel<<<8192, 256, 0, stream>>>(kern, mask, bm, mb);
    qkv_gemm_kernel<<<dim3(32, 8, 3), 256, 0, stream>>>(query, key_, value, ipw, ipb, qb, kb, vtb);
    attn_kernel<<<dim3(16, 32, 2), 256, 0, stream>>>(qb, kb, vtb, bm, mb, pO, pm, pl);
    out_gemm_kernel<<<dim3(64, 8), 256, 0, stream>>>(pO, pm, pl, outw, outb, (float*)d_out);
}